// Round 2
// baseline (674.178 us; speedup 1.0000x reference)
//
#include <hip/hip_runtime.h>
#include <hip/hip_bf16.h>
#include <math.h>

#define LOG2E 1.4426950408889634f

typedef __attribute__((ext_vector_type(8))) short short8_t;
typedef __attribute__((ext_vector_type(4))) float float4_t;

union Frag { short8_t f; unsigned u[4]; };

__device__ inline unsigned pack_bf16(float lo, float hi){
  union { __hip_bfloat162 h2; unsigned u; } cv;
  cv.h2 = __float22bfloat162_rn(make_float2(lo, hi));
  return cv.u;
}

// ---------------- K1: 1x1 convs, 4-way output split for parallelism.
// qs: [b][n][8] fp32 (log2e folded); kk: [b][8][n] fp32; vT: [b][64][n] bf16.
__global__ __launch_bounds__(256) void k1_qkv(
    const float* __restrict__ x, const float* __restrict__ wq, const float* __restrict__ bq,
    const float* __restrict__ wk, const float* __restrict__ bk,
    const float* __restrict__ wv, const float* __restrict__ bv,
    float* __restrict__ qs, float* __restrict__ kk, unsigned short* __restrict__ vT,
    float* __restrict__ regout)
{
  int tid = blockIdx.x*256 + threadIdx.x;   // 65536 threads
  if (tid == 0) regout[0] = 0.f;            // reg output: amap is analytically constant
  int g = tid >> 14;                        // output group 0..3 (uniform per block)
  int p = tid & 16383;
  int b = p >> 12, n = p & 4095;
  const float* xp = x + (size_t)b*64*4096 + n;
  float xr[64];
  #pragma unroll
  for (int c=0;c<64;++c) xr[c] = xp[(size_t)c*4096];

  if (g == 0){
    float* qp = qs + ((size_t)b*4096 + n)*8;
    #pragma unroll
    for (int u=0;u<8;++u){
      const float* wr = wq + u*64;
      float a0=0,a1=0,a2=0,a3=0;
      #pragma unroll
      for (int c=0;c<64;c+=4){ a0=fmaf(wr[c],xr[c],a0); a1=fmaf(wr[c+1],xr[c+1],a1);
                               a2=fmaf(wr[c+2],xr[c+2],a2); a3=fmaf(wr[c+3],xr[c+3],a3); }
      qp[u] = (bq[u] + ((a0+a1)+(a2+a3))) * LOG2E;
    }
    #pragma unroll
    for (int u=0;u<8;++u){
      const float* wr = wk + u*64;
      float a0=0,a1=0,a2=0,a3=0;
      #pragma unroll
      for (int c=0;c<64;c+=4){ a0=fmaf(wr[c],xr[c],a0); a1=fmaf(wr[c+1],xr[c+1],a1);
                               a2=fmaf(wr[c+2],xr[c+2],a2); a3=fmaf(wr[c+3],xr[c+3],a3); }
      kk[((size_t)b*8+u)*4096 + n] = bk[u] + ((a0+a1)+(a2+a3));
    }
  } else {
    int c0 = (g==1) ? 0 : (g==2) ? 22 : 43;
    int c1 = (g==1) ? 22 : (g==2) ? 43 : 64;
    for (int u=c0; u<c1; ++u){
      const float* wr = wv + u*64;
      float a0=0,a1=0,a2=0,a3=0;
      #pragma unroll
      for (int c=0;c<64;c+=4){ a0=fmaf(wr[c],xr[c],a0); a1=fmaf(wr[c+1],xr[c+1],a1);
                               a2=fmaf(wr[c+2],xr[c+2],a2); a3=fmaf(wr[c+3],xr[c+3],a3); }
      float res = bv[u] + ((a0+a1)+(a2+a3));
      __hip_bfloat16 h = __float2bfloat16(res);
      vT[((size_t)b*64+u)*4096 + n] = *(unsigned short*)&h;
    }
  }
}

// ---------------- K3: fully fused. Block = 512 thr = 8 waves; 16 rows/block,
// each wave owns a 512-wide j-slice.
// R2: __launch_bounds__(512,6) -> VGPR cap 85 (was 64->32 used: register-starved
// MLP exposed the 900cy noise-HBM latency serially). Depth-2 rotating-register
// prefetch of the noise stream (4 named buffers, no runtime indexing); vT loads
// hoisted to body top so their L2 latency hides under the s/p VALU chain.
// Numerics bit-identical to R1.
__global__ __launch_bounds__(512, 6) void k3_fused(
    const float* __restrict__ qs, const float* __restrict__ kk,
    const unsigned short* __restrict__ vT, const float* __restrict__ noise,
    const float* __restrict__ fwp, float* __restrict__ out)
{
  __shared__ float lds_l[8][16];
  __shared__ float lds_acc[8][16][64];
  int bid = blockIdx.x;                 // 1024 blocks: b = bid>>8, 16 rows each
  int b = bid >> 8; int i0 = (bid & 255) * 16;
  int t = threadIdx.x; int w = t >> 6; int lane = t & 63;
  int li = lane & 15, q4 = lane >> 4;
  int row = i0 + li;
  int jbase = w * 512;

  const float* qp = qs + ((size_t)b*4096 + row)*8;
  float qv[8];
  #pragma unroll
  for (int c=0;c<8;++c) qv[c] = qp[c];
  const float* kkb = kk + (size_t)b*8*4096;
  const float* nzr = noise + ((size_t)b*4096 + row)*4096;
  const unsigned short* vTb = vT + (size_t)b*64*4096;

  // ---- pass A: l1 over this wave's j-slice
  float l1 = 0.f;
  for (int sc=0; sc<16; ++sc){
    int j0 = jbase + sc*32 + q4*8;
    float s0=0,s1=0,s2=0,s3=0,s4=0,s5=0,s6=0,s7=0;
    #pragma unroll
    for (int c=0;c<8;++c){
      const float4* kp = (const float4*)(kkb + (size_t)c*4096 + j0);
      float4 ka = kp[0], kb2 = kp[1];
      float q = qv[c];
      s0=fmaf(q,ka.x,s0); s1=fmaf(q,ka.y,s1); s2=fmaf(q,ka.z,s2); s3=fmaf(q,ka.w,s3);
      s4=fmaf(q,kb2.x,s4); s5=fmaf(q,kb2.y,s5); s6=fmaf(q,kb2.z,s6); s7=fmaf(q,kb2.w,s7);
    }
    l1 += exp2f(s0-25.f); l1 += exp2f(s1-25.f); l1 += exp2f(s2-25.f); l1 += exp2f(s3-25.f);
    l1 += exp2f(s4-25.f); l1 += exp2f(s5-25.f); l1 += exp2f(s6-25.f); l1 += exp2f(s7-25.f);
  }
  l1 += __shfl_xor(l1, 16); l1 += __shfl_xor(l1, 32);
  if (lane < 16) lds_l[w][li] = l1;
  __syncthreads();
  float l1tot = 0.f;
  #pragma unroll
  for (int ww=0; ww<8; ++ww) l1tot += lds_l[ww][li];
  float c1 = LOG2E / l1tot;
  float ncoef = 0.1f * fwp[0] * LOG2E;

  // ---- pass B: p = exp2(e1*c1 + ncoef*noise - 2); PV via MFMA; l2 per row
  float4_t acc0 = {0.f,0.f,0.f,0.f}, acc1 = acc0, acc2 = acc0, acc3 = acc0;
  float l2 = 0.f;
  const unsigned short* vbase = vTb + (size_t)li*4096;

  // depth-2 noise prefetch, 4 named rotating buffers (rule #20: no runtime idx)
  float4 nA0,nA1,nB0,nB1,nC0,nC1,nD0,nD1;
  { const float4* np=(const float4*)(nzr + jbase      + q4*8); nA0=np[0]; nA1=np[1]; }
  { const float4* np=(const float4*)(nzr + jbase + 32 + q4*8); nB0=np[0]; nB1=np[1]; }

  auto bodyB = [&](int sc, float4 n0, float4 n1, float4& pf0, float4& pf1){
    int j0 = jbase + sc*32 + q4*8;
    // prefetch noise for sc+2 (HBM ~900cy) — lands 2 iterations later
    if (sc < 14){ const float4* np=(const float4*)(nzr + j0 + 64); pf0=np[0]; pf1=np[1]; }
    // vT loads issued early: L2 latency hides under the s/p VALU chain below
    const unsigned short* vp = vbase + j0;
    short8_t b0 = *(const short8_t*)(vp);
    short8_t b1 = *(const short8_t*)(vp + 16*4096);
    short8_t b2 = *(const short8_t*)(vp + 32*4096);
    short8_t b3 = *(const short8_t*)(vp + 48*4096);
    float s0=0,s1=0,s2=0,s3=0,s4=0,s5=0,s6=0,s7=0;
    #pragma unroll
    for (int c=0;c<8;++c){
      const float4* kp = (const float4*)(kkb + (size_t)c*4096 + j0);
      float4 ka = kp[0], kb2 = kp[1];
      float q = qv[c];
      s0=fmaf(q,ka.x,s0); s1=fmaf(q,ka.y,s1); s2=fmaf(q,ka.z,s2); s3=fmaf(q,ka.w,s3);
      s4=fmaf(q,kb2.x,s4); s5=fmaf(q,kb2.y,s5); s6=fmaf(q,kb2.z,s6); s7=fmaf(q,kb2.w,s7);
    }
    float p0,p1,p2,p3,p4,p5,p6,p7;
    p0 = exp2f(fmaf(ncoef,n0.x, fmaf(exp2f(s0-25.f), c1, -2.f)));
    p1 = exp2f(fmaf(ncoef,n0.y, fmaf(exp2f(s1-25.f), c1, -2.f)));
    p2 = exp2f(fmaf(ncoef,n0.z, fmaf(exp2f(s2-25.f), c1, -2.f)));
    p3 = exp2f(fmaf(ncoef,n0.w, fmaf(exp2f(s3-25.f), c1, -2.f)));
    p4 = exp2f(fmaf(ncoef,n1.x, fmaf(exp2f(s4-25.f), c1, -2.f)));
    p5 = exp2f(fmaf(ncoef,n1.y, fmaf(exp2f(s5-25.f), c1, -2.f)));
    p6 = exp2f(fmaf(ncoef,n1.z, fmaf(exp2f(s6-25.f), c1, -2.f)));
    p7 = exp2f(fmaf(ncoef,n1.w, fmaf(exp2f(s7-25.f), c1, -2.f)));
    l2 += ((p0+p1)+(p2+p3)) + ((p4+p5)+(p6+p7));
    Frag af;
    af.u[0] = pack_bf16(p0,p1); af.u[1] = pack_bf16(p2,p3);
    af.u[2] = pack_bf16(p4,p5); af.u[3] = pack_bf16(p6,p7);
    acc0 = __builtin_amdgcn_mfma_f32_16x16x32_bf16(af.f, b0, acc0, 0, 0, 0);
    acc1 = __builtin_amdgcn_mfma_f32_16x16x32_bf16(af.f, b1, acc1, 0, 0, 0);
    acc2 = __builtin_amdgcn_mfma_f32_16x16x32_bf16(af.f, b2, acc2, 0, 0, 0);
    acc3 = __builtin_amdgcn_mfma_f32_16x16x32_bf16(af.f, b3, acc3, 0, 0, 0);
  };

  for (int g4=0; g4<4; ++g4){
    bodyB(g4*4+0, nA0,nA1, nC0,nC1);
    bodyB(g4*4+1, nB0,nB1, nD0,nD1);
    bodyB(g4*4+2, nC0,nC1, nA0,nA1);
    bodyB(g4*4+3, nD0,nD1, nB0,nB1);
  }

  l2 += __shfl_xor(l2, 16); l2 += __shfl_xor(l2, 32);
  __syncthreads();                       // all waves done reading lds_l(l1)
  if (lane < 16) lds_l[w][li] = l2;
  // acc C/D layout: lane holds D[row=q4*4+reg][col=li]; col is the c-index tile
  #pragma unroll
  for (int reg=0; reg<4; ++reg){
    int rr = q4*4 + reg;
    lds_acc[w][rr][ 0 + li] = acc0[reg];
    lds_acc[w][rr][16 + li] = acc1[reg];
    lds_acc[w][rr][32 + li] = acc2[reg];
    lds_acc[w][rr][48 + li] = acc3[reg];
  }
  __syncthreads();
  // merge 8 j-slices + scale by 1/l2, write out[b][c][i0..i0+15]
  if (t < 256){
    int c = t >> 2, rg = t & 3;          // thread: one c, 4 consecutive rows
    float4 o;
    float* op = (float*)&o;
    #pragma unroll
    for (int r=0;r<4;++r){
      int rr = rg*4 + r;
      float vsum = 0.f, l2t = 0.f;
      #pragma unroll
      for (int ww=0; ww<8; ++ww){ vsum += lds_acc[ww][rr][c]; l2t += lds_l[ww][rr]; }
      op[r] = vsum / l2t;
    }
    *(float4*)(out + ((size_t)b*64 + c)*4096 + i0 + rg*4) = o;
  }
}

extern "C" void kernel_launch(void* const* d_in, const int* in_sizes, int n_in,
                              void* d_out, int out_size, void* d_ws, size_t ws_size,
                              hipStream_t stream) {
  const float* x     = (const float*)d_in[0];
  const float* wq    = (const float*)d_in[1];
  const float* bq    = (const float*)d_in[2];
  const float* wk    = (const float*)d_in[3];
  const float* bk    = (const float*)d_in[4];
  const float* wv    = (const float*)d_in[5];
  const float* bv    = (const float*)d_in[6];
  const float* fw    = (const float*)d_in[7];
  const float* noise = (const float*)d_in[8];
  float* out = (float*)d_out;
  float* ws  = (float*)d_ws;
  // scratch (floats): qs 131072 | kk 131072 | vT 524288 (1M ushort)
  float* qs = ws;
  float* kk = ws + 131072;
  unsigned short* vT = (unsigned short*)(ws + 262144);

  hipLaunchKernelGGL(k1_qkv,   dim3(256),  dim3(256), 0, stream,
                     x,wq,bq,wk,bk,wv,bv,qs,kk,vT, out + 1048576);
  hipLaunchKernelGGL(k3_fused, dim3(1024), dim3(512), 0, stream,
                     qs,kk,vT,noise,fw,out);
}

// Round 3
// 577.447 us; speedup vs baseline: 1.1675x; 1.1675x over previous
//
#include <hip/hip_runtime.h>
#include <hip/hip_bf16.h>
#include <math.h>

#define LOG2E 1.4426950408889634f

typedef __attribute__((ext_vector_type(8))) short short8_t;
typedef __attribute__((ext_vector_type(4))) float float4_t;

union Frag { short8_t f; unsigned u[4]; };

__device__ inline unsigned pack_bf16(float lo, float hi){
  union { __hip_bfloat162 h2; unsigned u; } cv;
  cv.h2 = __float22bfloat162_rn(make_float2(lo, hi));
  return cv.u;
}

// ---------------- K1: 1x1 convs, 8-way output split (was 4): 512 blocks ->
// 2 blocks/CU, halves per-thread serial work. Numerics per-output unchanged.
// qs: [b][n][8] fp32 (log2e folded); kk: [b][8][n] fp32; vT: [b][64][n] bf16.
__global__ __launch_bounds__(256) void k1_qkv(
    const float* __restrict__ x, const float* __restrict__ wq, const float* __restrict__ bq,
    const float* __restrict__ wk, const float* __restrict__ bk,
    const float* __restrict__ wv, const float* __restrict__ bv,
    float* __restrict__ qs, float* __restrict__ kk, unsigned short* __restrict__ vT,
    float* __restrict__ regout)
{
  int tid = blockIdx.x*256 + threadIdx.x;   // 131072 threads
  if (tid == 0) regout[0] = 0.f;            // reg output: amap is analytically constant
  int g = tid >> 14;                        // output group 0..7 (uniform per block)
  int p = tid & 16383;
  int b = p >> 12, n = p & 4095;
  const float* xp = x + (size_t)b*64*4096 + n;
  float xr[64];
  #pragma unroll
  for (int c=0;c<64;++c) xr[c] = xp[(size_t)c*4096];

  if (g == 0){
    float* qp = qs + ((size_t)b*4096 + n)*8;
    #pragma unroll
    for (int u=0;u<8;++u){
      const float* wr = wq + u*64;
      float a0=0,a1=0,a2=0,a3=0;
      #pragma unroll
      for (int c=0;c<64;c+=4){ a0=fmaf(wr[c],xr[c],a0); a1=fmaf(wr[c+1],xr[c+1],a1);
                               a2=fmaf(wr[c+2],xr[c+2],a2); a3=fmaf(wr[c+3],xr[c+3],a3); }
      qp[u] = (bq[u] + ((a0+a1)+(a2+a3))) * LOG2E;
    }
  } else if (g == 1){
    #pragma unroll
    for (int u=0;u<8;++u){
      const float* wr = wk + u*64;
      float a0=0,a1=0,a2=0,a3=0;
      #pragma unroll
      for (int c=0;c<64;c+=4){ a0=fmaf(wr[c],xr[c],a0); a1=fmaf(wr[c+1],xr[c+1],a1);
                               a2=fmaf(wr[c+2],xr[c+2],a2); a3=fmaf(wr[c+3],xr[c+3],a3); }
      kk[((size_t)b*8+u)*4096 + n] = bk[u] + ((a0+a1)+(a2+a3));
    }
  } else {
    int c0 = ((g-2)*64)/6;                 // {0,10,21,32,42,53}
    int c1v = ((g-1)*64)/6;                // {10,21,32,42,53,64}
    for (int u=c0; u<c1v; ++u){
      const float* wr = wv + u*64;
      float a0=0,a1=0,a2=0,a3=0;
      #pragma unroll
      for (int c=0;c<64;c+=4){ a0=fmaf(wr[c],xr[c],a0); a1=fmaf(wr[c+1],xr[c+1],a1);
                               a2=fmaf(wr[c+2],xr[c+2],a2); a3=fmaf(wr[c+3],xr[c+3],a3); }
      float res = bv[u] + ((a0+a1)+(a2+a3));
      __hip_bfloat16 h = __float2bfloat16(res);
      vT[((size_t)b*64+u)*4096 + n] = *(unsigned short*)&h;
    }
  }
}

// ---------------- K3: fully fused. Block = 512 thr = 8 waves; 16 rows/block,
// each wave owns a 512-wide j-slice.
// R3: plain straight-line depth-1 noise prefetch (named A/B float4s, no lambda,
// no refs, no runtime-indexed arrays -> no scratch; R2's 368MB WRITE_SIZE spill
// came from the lambda rotation). vT loads hoisted to top of each half so L2
// latency hides under the dot/exp chain. __launch_bounds__(512,6): 85-VGPR cap,
// 3 blocks/CU (75% occ) -> compiler has headroom to keep prefetches in flight.
// Numerics bit-identical to R1.

#define PB_DOT(J0) \
    float s0=0,s1=0,s2=0,s3=0,s4=0,s5=0,s6=0,s7=0; \
    _Pragma("unroll") \
    for (int c=0;c<8;++c){ \
      const float4* kp = (const float4*)(kkb + (size_t)c*4096 + (J0)); \
      float4 ka = kp[0], kb2 = kp[1]; \
      float q = qv[c]; \
      s0=fmaf(q,ka.x,s0); s1=fmaf(q,ka.y,s1); s2=fmaf(q,ka.z,s2); s3=fmaf(q,ka.w,s3); \
      s4=fmaf(q,kb2.x,s4); s5=fmaf(q,kb2.y,s5); s6=fmaf(q,kb2.z,s6); s7=fmaf(q,kb2.w,s7); \
    }

#define PB_PVAL(N0, N1) \
    float p0 = exp2f(fmaf(ncoef,(N0).x, fmaf(exp2f(s0-25.f), c1, -2.f))); \
    float p1 = exp2f(fmaf(ncoef,(N0).y, fmaf(exp2f(s1-25.f), c1, -2.f))); \
    float p2 = exp2f(fmaf(ncoef,(N0).z, fmaf(exp2f(s2-25.f), c1, -2.f))); \
    float p3 = exp2f(fmaf(ncoef,(N0).w, fmaf(exp2f(s3-25.f), c1, -2.f))); \
    float p4 = exp2f(fmaf(ncoef,(N1).x, fmaf(exp2f(s4-25.f), c1, -2.f))); \
    float p5 = exp2f(fmaf(ncoef,(N1).y, fmaf(exp2f(s5-25.f), c1, -2.f))); \
    float p6 = exp2f(fmaf(ncoef,(N1).z, fmaf(exp2f(s6-25.f), c1, -2.f))); \
    float p7 = exp2f(fmaf(ncoef,(N1).w, fmaf(exp2f(s7-25.f), c1, -2.f)));

#define PB_TAIL(B0,B1,B2,B3) \
    l2 += ((p0+p1)+(p2+p3)) + ((p4+p5)+(p6+p7)); \
    Frag af; \
    af.u[0] = pack_bf16(p0,p1); af.u[1] = pack_bf16(p2,p3); \
    af.u[2] = pack_bf16(p4,p5); af.u[3] = pack_bf16(p6,p7); \
    acc0 = __builtin_amdgcn_mfma_f32_16x16x32_bf16(af.f, (B0), acc0, 0, 0, 0); \
    acc1 = __builtin_amdgcn_mfma_f32_16x16x32_bf16(af.f, (B1), acc1, 0, 0, 0); \
    acc2 = __builtin_amdgcn_mfma_f32_16x16x32_bf16(af.f, (B2), acc2, 0, 0, 0); \
    acc3 = __builtin_amdgcn_mfma_f32_16x16x32_bf16(af.f, (B3), acc3, 0, 0, 0);

__global__ __launch_bounds__(512, 6) void k3_fused(
    const float* __restrict__ qs, const float* __restrict__ kk,
    const unsigned short* __restrict__ vT, const float* __restrict__ noise,
    const float* __restrict__ fwp, float* __restrict__ out)
{
  __shared__ float lds_l[8][16];
  __shared__ float lds_acc[8][16][64];
  int bid = blockIdx.x;                 // 1024 blocks: b = bid>>8, 16 rows each
  int b = bid >> 8; int i0 = (bid & 255) * 16;
  int t = threadIdx.x; int w = t >> 6; int lane = t & 63;
  int li = lane & 15, q4 = lane >> 4;
  int row = i0 + li;
  int jbase = w * 512;

  const float* qp = qs + ((size_t)b*4096 + row)*8;
  float qv[8];
  #pragma unroll
  for (int c=0;c<8;++c) qv[c] = qp[c];
  const float* kkb = kk + (size_t)b*8*4096;
  const float* nzr = noise + ((size_t)b*4096 + row)*4096;
  const unsigned short* vTb = vT + (size_t)b*64*4096;

  // ---- pass A: l1 over this wave's j-slice
  float l1 = 0.f;
  for (int sc=0; sc<16; ++sc){
    int j0 = jbase + sc*32 + q4*8;
    PB_DOT(j0)
    l1 += exp2f(s0-25.f); l1 += exp2f(s1-25.f); l1 += exp2f(s2-25.f); l1 += exp2f(s3-25.f);
    l1 += exp2f(s4-25.f); l1 += exp2f(s5-25.f); l1 += exp2f(s6-25.f); l1 += exp2f(s7-25.f);
  }
  l1 += __shfl_xor(l1, 16); l1 += __shfl_xor(l1, 32);
  if (lane < 16) lds_l[w][li] = l1;
  __syncthreads();
  float l1tot = 0.f;
  #pragma unroll
  for (int ww=0; ww<8; ++ww) l1tot += lds_l[ww][li];
  float c1 = LOG2E / l1tot;
  float ncoef = 0.1f * fwp[0] * LOG2E;

  // ---- pass B: p = exp2(e1*c1 + ncoef*noise - 2); PV via MFMA; l2 per row
  float4_t acc0 = {0.f,0.f,0.f,0.f}, acc1 = acc0, acc2 = acc0, acc3 = acc0;
  float l2 = 0.f;
  const unsigned short* vbase = vTb + (size_t)li*4096;

  // prologue: noise for sc=0 (A) and sc=1 (B)
  float4 nA0,nA1,nB0,nB1;
  { const float4* np=(const float4*)(nzr + jbase      + q4*8); nA0=np[0]; nA1=np[1]; }
  { const float4* np=(const float4*)(nzr + jbase + 32 + q4*8); nB0=np[0]; nB1=np[1]; }

  for (int sp=0; sp<8; ++sp){
    int scA = sp*2;
    { // ---- half A: compute scA from nA; refill nA for scA+2
      int j0 = jbase + scA*32 + q4*8;
      const unsigned short* vp = vbase + j0;
      short8_t b0 = *(const short8_t*)(vp);
      short8_t b1 = *(const short8_t*)(vp + 16*4096);
      short8_t b2 = *(const short8_t*)(vp + 32*4096);
      short8_t b3 = *(const short8_t*)(vp + 48*4096);
      PB_DOT(j0)
      PB_PVAL(nA0, nA1)
      int scN = (sp < 7) ? (scA + 2) : (scA + 1);   // last pair: re-read hot line, dead value
      { const float4* np=(const float4*)(nzr + jbase + scN*32 + q4*8); nA0=np[0]; nA1=np[1]; }
      PB_TAIL(b0,b1,b2,b3)
    }
    { // ---- half B: compute scA+1 from nB; refill nB for scA+3
      int j0 = jbase + (scA+1)*32 + q4*8;
      const unsigned short* vp = vbase + j0;
      short8_t b0 = *(const short8_t*)(vp);
      short8_t b1 = *(const short8_t*)(vp + 16*4096);
      short8_t b2 = *(const short8_t*)(vp + 32*4096);
      short8_t b3 = *(const short8_t*)(vp + 48*4096);
      PB_DOT(j0)
      PB_PVAL(nB0, nB1)
      int scN = (sp < 7) ? (scA + 3) : (scA + 1);   // last pair: re-read hot line, dead value
      { const float4* np=(const float4*)(nzr + jbase + scN*32 + q4*8); nB0=np[0]; nB1=np[1]; }
      PB_TAIL(b0,b1,b2,b3)
    }
  }

  l2 += __shfl_xor(l2, 16); l2 += __shfl_xor(l2, 32);
  __syncthreads();                       // all waves done reading lds_l(l1)
  if (lane < 16) lds_l[w][li] = l2;
  // acc C/D layout: lane holds D[row=q4*4+reg][col=li]; col is the c-index tile
  #pragma unroll
  for (int reg=0; reg<4; ++reg){
    int rr = q4*4 + reg;
    lds_acc[w][rr][ 0 + li] = acc0[reg];
    lds_acc[w][rr][16 + li] = acc1[reg];
    lds_acc[w][rr][32 + li] = acc2[reg];
    lds_acc[w][rr][48 + li] = acc3[reg];
  }
  __syncthreads();
  // merge 8 j-slices + scale by 1/l2, write out[b][c][i0..i0+15]
  if (t < 256){
    int c = t >> 2, rg = t & 3;          // thread: one c, 4 consecutive rows
    float4 o;
    float* op = (float*)&o;
    #pragma unroll
    for (int r=0;r<4;++r){
      int rr = rg*4 + r;
      float vsum = 0.f, l2t = 0.f;
      #pragma unroll
      for (int ww=0; ww<8; ++ww){ vsum += lds_acc[ww][rr][c]; l2t += lds_l[ww][rr]; }
      op[r] = vsum / l2t;
    }
    *(float4*)(out + ((size_t)b*64 + c)*4096 + i0 + rg*4) = o;
  }
}

extern "C" void kernel_launch(void* const* d_in, const int* in_sizes, int n_in,
                              void* d_out, int out_size, void* d_ws, size_t ws_size,
                              hipStream_t stream) {
  const float* x     = (const float*)d_in[0];
  const float* wq    = (const float*)d_in[1];
  const float* bq    = (const float*)d_in[2];
  const float* wk    = (const float*)d_in[3];
  const float* bk    = (const float*)d_in[4];
  const float* wv    = (const float*)d_in[5];
  const float* bv    = (const float*)d_in[6];
  const float* fw    = (const float*)d_in[7];
  const float* noise = (const float*)d_in[8];
  float* out = (float*)d_out;
  float* ws  = (float*)d_ws;
  // scratch (floats): qs 131072 | kk 131072 | vT 524288 (1M ushort)
  float* qs = ws;
  float* kk = ws + 131072;
  unsigned short* vT = (unsigned short*)(ws + 262144);

  hipLaunchKernelGGL(k1_qkv,   dim3(512),  dim3(256), 0, stream,
                     x,wq,bq,wk,bk,wv,bv,qs,kk,vT, out + 1048576);
  hipLaunchKernelGGL(k3_fused, dim3(1024), dim3(512), 0, stream,
                     qs,kk,vT,noise,fw,out);
}

// Round 4
// 540.763 us; speedup vs baseline: 1.2467x; 1.0678x over previous
//
#include <hip/hip_runtime.h>
#include <hip/hip_bf16.h>
#include <math.h>

#define LOG2E 1.4426950408889634f

typedef __attribute__((ext_vector_type(8))) short short8_t;
typedef __attribute__((ext_vector_type(4))) float float4_t;

union Frag { short8_t f; unsigned u[4]; };

__device__ inline unsigned pack_bf16(float lo, float hi){
  union { __hip_bfloat162 h2; unsigned u; } cv;
  cv.h2 = __float22bfloat162_rn(make_float2(lo, hi));
  return cv.u;
}

// ---------------- K1: 1x1 convs, 16-way output split: 1024 blocks -> 4/CU.
// qs: [b][n][8] fp32 (log2e folded); kk: [b][8][n] fp32; vT: [b][64][n] bf16.
__global__ __launch_bounds__(256) void k1_qkv(
    const float* __restrict__ x, const float* __restrict__ wq, const float* __restrict__ bq,
    const float* __restrict__ wk, const float* __restrict__ bk,
    const float* __restrict__ wv, const float* __restrict__ bv,
    float* __restrict__ qs, float* __restrict__ kk, unsigned short* __restrict__ vT,
    float* __restrict__ regout)
{
  int tid = blockIdx.x*256 + threadIdx.x;   // 262144 threads
  if (tid == 0) regout[0] = 0.f;            // reg output: amap is analytically constant
  int g = tid >> 14;                        // output group 0..15 (uniform per block)
  int p = tid & 16383;
  int b = p >> 12, n = p & 4095;
  const float* xp = x + (size_t)b*64*4096 + n;
  float xr[64];
  #pragma unroll
  for (int c=0;c<64;++c) xr[c] = xp[(size_t)c*4096];

  if (g < 2){                               // q outputs, 4 per group
    float* qp = qs + ((size_t)b*4096 + n)*8;
    int u0 = g*4;
    #pragma unroll
    for (int uu=0;uu<4;++uu){
      int u = u0 + uu;
      const float* wr = wq + u*64;
      float a0=0,a1=0,a2=0,a3=0;
      #pragma unroll
      for (int c=0;c<64;c+=4){ a0=fmaf(wr[c],xr[c],a0); a1=fmaf(wr[c+1],xr[c+1],a1);
                               a2=fmaf(wr[c+2],xr[c+2],a2); a3=fmaf(wr[c+3],xr[c+3],a3); }
      qp[u] = (bq[u] + ((a0+a1)+(a2+a3))) * LOG2E;
    }
  } else if (g < 4){                        // k outputs, 4 per group
    int u0 = (g-2)*4;
    #pragma unroll
    for (int uu=0;uu<4;++uu){
      int u = u0 + uu;
      const float* wr = wk + u*64;
      float a0=0,a1=0,a2=0,a3=0;
      #pragma unroll
      for (int c=0;c<64;c+=4){ a0=fmaf(wr[c],xr[c],a0); a1=fmaf(wr[c+1],xr[c+1],a1);
                               a2=fmaf(wr[c+2],xr[c+2],a2); a3=fmaf(wr[c+3],xr[c+3],a3); }
      kk[((size_t)b*8+u)*4096 + n] = bk[u] + ((a0+a1)+(a2+a3));
    }
  } else {                                  // v outputs, <=6 per group (12 groups)
    int c0 = ((g-4)*64)/12;
    int c1v = ((g-3)*64)/12;
    for (int u=c0; u<c1v; ++u){
      const float* wr = wv + u*64;
      float a0=0,a1=0,a2=0,a3=0;
      #pragma unroll
      for (int c=0;c<64;c+=4){ a0=fmaf(wr[c],xr[c],a0); a1=fmaf(wr[c+1],xr[c+1],a1);
                               a2=fmaf(wr[c+2],xr[c+2],a2); a3=fmaf(wr[c+3],xr[c+3],a3); }
      float res = bv[u] + ((a0+a1)+(a2+a3));
      __hip_bfloat16 h = __float2bfloat16(res);
      vT[((size_t)b*64+u)*4096 + n] = *(unsigned short*)&h;
    }
  }
}

// ---------------- K3: fully fused. Block = 512 thr = 8 waves; 16 rows/block,
// each wave owns a 512-wide j-slice.
// R4: T19 sched_group_barrier clustering per iteration (VMEM cluster -> VALU ->
// VMEM(vT) -> VALU -> MFMA) + __launch_bounds__(512,4) (128-VGPR budget) so the
// forced load cluster fits in registers. The compiler then emits counted vmcnt
// waits instead of 6-8 serialized load-batch drains per iteration (R1/R3 showed
// VGPR_Count 32-40: scheduler sank loads, exposing ~200-900cy latency serially).
// Body reverted to R1's plain form. Numerics bit-identical to R1.

#define PB_DOT(J0) \
    float s0=0,s1=0,s2=0,s3=0,s4=0,s5=0,s6=0,s7=0; \
    _Pragma("unroll") \
    for (int c=0;c<8;++c){ \
      const float4* kp = (const float4*)(kkb + (size_t)c*4096 + (J0)); \
      float4 ka = kp[0], kb2 = kp[1]; \
      float q = qv[c]; \
      s0=fmaf(q,ka.x,s0); s1=fmaf(q,ka.y,s1); s2=fmaf(q,ka.z,s2); s3=fmaf(q,ka.w,s3); \
      s4=fmaf(q,kb2.x,s4); s5=fmaf(q,kb2.y,s5); s6=fmaf(q,kb2.z,s6); s7=fmaf(q,kb2.w,s7); \
    }

__global__ __launch_bounds__(512, 4) void k3_fused(
    const float* __restrict__ qs, const float* __restrict__ kk,
    const unsigned short* __restrict__ vT, const float* __restrict__ noise,
    const float* __restrict__ fwp, float* __restrict__ out)
{
  __shared__ float lds_l[8][16];
  __shared__ float lds_acc[8][16][64];
  int bid = blockIdx.x;                 // 1024 blocks: b = bid>>8, 16 rows each
  int b = bid >> 8; int i0 = (bid & 255) * 16;
  int t = threadIdx.x; int w = t >> 6; int lane = t & 63;
  int li = lane & 15, q4 = lane >> 4;
  int row = i0 + li;
  int jbase = w * 512;

  const float* qp = qs + ((size_t)b*4096 + row)*8;
  float qv[8];
  #pragma unroll
  for (int c=0;c<8;++c) qv[c] = qp[c];
  const float* kkb = kk + (size_t)b*8*4096;
  const float* nzr = noise + ((size_t)b*4096 + row)*4096;
  const unsigned short* vTb = vT + (size_t)b*64*4096;

  // ---- pass A: l1 over this wave's j-slice
  float l1 = 0.f;
  for (int sc=0; sc<16; ++sc){
    int j0 = jbase + sc*32 + q4*8;
    PB_DOT(j0)
    l1 += exp2f(s0-25.f); l1 += exp2f(s1-25.f); l1 += exp2f(s2-25.f); l1 += exp2f(s3-25.f);
    l1 += exp2f(s4-25.f); l1 += exp2f(s5-25.f); l1 += exp2f(s6-25.f); l1 += exp2f(s7-25.f);
    // T19: cluster the 16 kk loads, then the dot/exp VALU chain
    __builtin_amdgcn_sched_group_barrier(0x20, 16, 0);  // VMEM_READ
    __builtin_amdgcn_sched_group_barrier(0x02, 76, 0);  // VALU
  }
  l1 += __shfl_xor(l1, 16); l1 += __shfl_xor(l1, 32);
  if (lane < 16) lds_l[w][li] = l1;
  __syncthreads();
  float l1tot = 0.f;
  #pragma unroll
  for (int ww=0; ww<8; ++ww) l1tot += lds_l[ww][li];
  float c1 = LOG2E / l1tot;
  float ncoef = 0.1f * fwp[0] * LOG2E;

  // ---- pass B: p = exp2(e1*c1 + ncoef*noise - 2); PV via MFMA; l2 per row
  float4_t acc0 = {0.f,0.f,0.f,0.f}, acc1 = acc0, acc2 = acc0, acc3 = acc0;
  float l2 = 0.f;
  const unsigned short* vbase = vTb + (size_t)li*4096;

  for (int sc=0; sc<16; ++sc){
    int j0 = jbase + sc*32 + q4*8;
    const float4* np = (const float4*)(nzr + j0);
    float4 n0 = np[0], n1 = np[1];
    PB_DOT(j0)
    const unsigned short* vp = vbase + j0;
    short8_t b0 = *(const short8_t*)(vp);
    short8_t b1 = *(const short8_t*)(vp + 16*4096);
    short8_t b2 = *(const short8_t*)(vp + 32*4096);
    short8_t b3 = *(const short8_t*)(vp + 48*4096);
    float p0,p1,p2,p3,p4,p5,p6,p7;
    p0 = exp2f(fmaf(ncoef,n0.x, fmaf(exp2f(s0-25.f), c1, -2.f)));
    p1 = exp2f(fmaf(ncoef,n0.y, fmaf(exp2f(s1-25.f), c1, -2.f)));
    p2 = exp2f(fmaf(ncoef,n0.z, fmaf(exp2f(s2-25.f), c1, -2.f)));
    p3 = exp2f(fmaf(ncoef,n0.w, fmaf(exp2f(s3-25.f), c1, -2.f)));
    p4 = exp2f(fmaf(ncoef,n1.x, fmaf(exp2f(s4-25.f), c1, -2.f)));
    p5 = exp2f(fmaf(ncoef,n1.y, fmaf(exp2f(s5-25.f), c1, -2.f)));
    p6 = exp2f(fmaf(ncoef,n1.z, fmaf(exp2f(s6-25.f), c1, -2.f)));
    p7 = exp2f(fmaf(ncoef,n1.w, fmaf(exp2f(s7-25.f), c1, -2.f)));
    l2 += ((p0+p1)+(p2+p3)) + ((p4+p5)+(p6+p7));
    Frag af;
    af.u[0] = pack_bf16(p0,p1); af.u[1] = pack_bf16(p2,p3);
    af.u[2] = pack_bf16(p4,p5); af.u[3] = pack_bf16(p6,p7);
    acc0 = __builtin_amdgcn_mfma_f32_16x16x32_bf16(af.f, b0, acc0, 0, 0, 0);
    acc1 = __builtin_amdgcn_mfma_f32_16x16x32_bf16(af.f, b1, acc1, 0, 0, 0);
    acc2 = __builtin_amdgcn_mfma_f32_16x16x32_bf16(af.f, b2, acc2, 0, 0, 0);
    acc3 = __builtin_amdgcn_mfma_f32_16x16x32_bf16(af.f, b3, acc3, 0, 0, 0);
    // T19 per-iteration schedule: {kk+noise 18} {dots 60} {vT 4} {p/pack 48} {MFMA 4}
    __builtin_amdgcn_sched_group_barrier(0x20, 18, 0);  // VMEM_READ: kk + noise
    __builtin_amdgcn_sched_group_barrier(0x02, 60, 0);  // VALU: dot chain
    __builtin_amdgcn_sched_group_barrier(0x20,  4, 0);  // VMEM_READ: vT
    __builtin_amdgcn_sched_group_barrier(0x02, 48, 0);  // VALU: exp/p/pack/l2
    __builtin_amdgcn_sched_group_barrier(0x08,  4, 0);  // MFMA
  }

  l2 += __shfl_xor(l2, 16); l2 += __shfl_xor(l2, 32);
  __syncthreads();                       // all waves done reading lds_l(l1)
  if (lane < 16) lds_l[w][li] = l2;
  // acc C/D layout: lane holds D[row=q4*4+reg][col=li]; col is the c-index tile
  #pragma unroll
  for (int reg=0; reg<4; ++reg){
    int rr = q4*4 + reg;
    lds_acc[w][rr][ 0 + li] = acc0[reg];
    lds_acc[w][rr][16 + li] = acc1[reg];
    lds_acc[w][rr][32 + li] = acc2[reg];
    lds_acc[w][rr][48 + li] = acc3[reg];
  }
  __syncthreads();
  // merge 8 j-slices + scale by 1/l2, write out[b][c][i0..i0+15]
  if (t < 256){
    int c = t >> 2, rg = t & 3;          // thread: one c, 4 consecutive rows
    float4 o;
    float* op = (float*)&o;
    #pragma unroll
    for (int r=0;r<4;++r){
      int rr = rg*4 + r;
      float vsum = 0.f, l2t = 0.f;
      #pragma unroll
      for (int ww=0; ww<8; ++ww){ vsum += lds_acc[ww][rr][c]; l2t += lds_l[ww][rr]; }
      op[r] = vsum / l2t;
    }
    *(float4*)(out + ((size_t)b*64 + c)*4096 + i0 + rg*4) = o;
  }
}

extern "C" void kernel_launch(void* const* d_in, const int* in_sizes, int n_in,
                              void* d_out, int out_size, void* d_ws, size_t ws_size,
                              hipStream_t stream) {
  const float* x     = (const float*)d_in[0];
  const float* wq    = (const float*)d_in[1];
  const float* bq    = (const float*)d_in[2];
  const float* wk    = (const float*)d_in[3];
  const float* bk    = (const float*)d_in[4];
  const float* wv    = (const float*)d_in[5];
  const float* bv    = (const float*)d_in[6];
  const float* fw    = (const float*)d_in[7];
  const float* noise = (const float*)d_in[8];
  float* out = (float*)d_out;
  float* ws  = (float*)d_ws;
  // scratch (floats): qs 131072 | kk 131072 | vT 524288 (1M ushort)
  float* qs = ws;
  float* kk = ws + 131072;
  unsigned short* vT = (unsigned short*)(ws + 262144);

  hipLaunchKernelGGL(k1_qkv,   dim3(1024), dim3(256), 0, stream,
                     x,wq,bq,wk,bk,wv,bv,qs,kk,vT, out + 1048576);
  hipLaunchKernelGGL(k3_fused, dim3(1024), dim3(512), 0, stream,
                     qs,kk,vT,noise,fw,out);
}